// Round 2
// baseline (162.080 us; speedup 1.0000x reference)
//
#include <hip/hip_runtime.h>

// MVB (minimum-variance beamformer), fp32. Two-kernel split to kill scratch
// spills (round 1: 125 MB spill traffic, VGPR capped at 132 with Ru[136] live).
//
// Kernel A: per-pixel delay-align + rolling 16-lag window sums.
//   Writes F[16], win[16], head[16], Sall (49 floats/pixel) to d_ws,
//   feature-major (ws[f*NPIX + pix]) for coalescing. ~140 VGPRs, spill-free.
// Kernel B: R assembly (lag identity) + diagonal loading + Cholesky +
//   two triangular solves + weighted sum. Ru[136] in registers,
//   __launch_bounds__(256,1) -> up to 512 VGPRs, spill-free.

namespace {

constexpr int kB  = 2;
constexpr int kC  = 128;
constexpr int kNS = 1024;
constexpr int kNZ = 256;
constexpr int kNX = 128;
constexpr int kZX = kNZ * kNX;      // 32768
constexpr int kNPIX = kB * kZX;     // 65536
constexpr int kChunk = 8;           // rf rows per stage
constexpr int kTPB = 128;

// packed upper-triangular index, l <= k, 16x16 -> 136 entries
__device__ __host__ constexpr int tri(int l, int k) {
  return l * 16 - (l * (l - 1)) / 2 + (k - l);
}

template <int PH, bool HEAD>
__device__ __forceinline__ void chunk_compute(
    const float (&rows)[kChunk][kNS], int cbase,
    const float* __restrict__ drx_px, float kk, float base,
    float (&F)[16], float (&win)[16], float (&head)[16], float& Sall) {
  float drx[kChunk];
#pragma unroll
  for (int r = 0; r < kChunk; ++r)
    drx[r] = drx_px[(size_t)(cbase + r) * kZX];   // coalesced across lanes

#pragma unroll
  for (int r = 0; r < kChunk; ++r) {
    const int t = PH + r;                          // == c & 15 (static)
    float pos = fmaf(kk, drx[r], base);
    pos = fminf(fmaxf(pos, 0.0f), 1023.0f);
    int i0 = (int)pos;                             // pos >= 0: trunc == floor
    float frac = pos - (float)i0;
    int i1 = min(i0 + 1, kNS - 1);
    float v0 = rows[r][i0];                        // ds_read, random bank
    float v1 = rows[r][i1];
    float v = fmaf(frac, v1 - v0, v0);
    Sall += v;
    F[0] = fmaf(v, v, F[0]);
    if constexpr (HEAD) {
#pragma unroll
      for (int d = 1; d <= t; ++d) F[d] = fmaf(v, win[t - d], F[d]);
      head[t] = v;
    } else {
#pragma unroll
      for (int d = 1; d < 16; ++d) F[d] = fmaf(v, win[(t - d) & 15], F[d]);
    }
    win[t] = v;
  }
}

// ---------------- Kernel A: window accumulation ----------------
__global__ __launch_bounds__(kTPB) void mvb_window_kernel(
    const float* __restrict__ rf, const float* __restrict__ t0,
    const float* __restrict__ d_tx, const float* __restrict__ d_rx,
    const float* __restrict__ fs_p, const float* __restrict__ c0_p,
    float* __restrict__ ws) {
  __shared__ float tile[2][kChunk][kNS];   // 64 KB -> 2 blocks/CU

  const int tid = threadIdx.x;
  const int z = blockIdx.x & (kNZ - 1);
  const int b = blockIdx.x >> 8;           // kNZ == 256
  const int x = tid;
  const int pix = (int)((size_t)b * kZX + z * kNX + x);

  const float fs = fs_p[0];
  const float c0 = c0_p[0];
  const float kk = fs / c0;
  const float base =
      fs * (d_tx[(size_t)b * kZX + z * kNX + x] / c0 + t0[b]);

  const float* rfb = rf + (size_t)b * kC * kNS;
  const float* drx_px = d_rx + (size_t)z * kNX + x;   // + c*kZX per channel

  float F[16], win[16], head[16];
  float Sall = 0.0f;
#pragma unroll
  for (int i = 0; i < 16; ++i) F[i] = 0.0f;

  float4 pre[kChunk * 2];   // prefetched rf chunk (2 float4 per row per thread)
  auto prefetch = [&](int q) {
    const float* src = rfb + (size_t)q * kChunk * kNS;
#pragma unroll
    for (int r = 0; r < kChunk; ++r) {
      pre[r * 2 + 0] =
          *reinterpret_cast<const float4*>(src + r * kNS + tid * 4);
      pre[r * 2 + 1] =
          *reinterpret_cast<const float4*>(src + r * kNS + 512 + tid * 4);
    }
  };
  auto stage = [&](int buf) {
#pragma unroll
    for (int r = 0; r < kChunk; ++r) {
      *reinterpret_cast<float4*>(&tile[buf][r][tid * 4]) = pre[r * 2 + 0];
      *reinterpret_cast<float4*>(&tile[buf][r][512 + tid * 4]) = pre[r * 2 + 1];
    }
  };

  // ---- pipelined main loop over 16 chunks of 8 channels ----
  prefetch(0);
  stage(0);
  prefetch(1);
  __syncthreads();
  chunk_compute<0, true>(tile[0], 0, drx_px, kk, base, F, win, head, Sall);

  __syncthreads();
  stage(1);
  prefetch(2);
  __syncthreads();
  chunk_compute<8, true>(tile[1], 8, drx_px, kk, base, F, win, head, Sall);

  for (int g = 1; g < 8; ++g) {
    const int q0 = 2 * g;
    __syncthreads();                       // readers of tile[0] (chunk q0-2) done
    stage(0);
    prefetch(q0 + 1);
    __syncthreads();                       // tile[0] visible
    chunk_compute<0, false>(tile[0], q0 * kChunk, drx_px, kk, base, F, win,
                            head, Sall);

    __syncthreads();
    stage(1);
    if (q0 + 2 < 16) prefetch(q0 + 2);
    __syncthreads();
    chunk_compute<8, false>(tile[1], (q0 + 1) * kChunk, drx_px, kk, base, F,
                            win, head, Sall);
  }
  // now: head[i] = xf[i], win[i] = xf[112+i], F[d] = sum_j xf[j]*xf[j-d]

  // ---- write per-pixel summary, feature-major for coalescing ----
#pragma unroll
  for (int i = 0; i < 16; ++i) ws[(size_t)i * kNPIX + pix] = F[i];
#pragma unroll
  for (int i = 0; i < 16; ++i) ws[(size_t)(16 + i) * kNPIX + pix] = win[i];
#pragma unroll
  for (int i = 0; i < 16; ++i) ws[(size_t)(32 + i) * kNPIX + pix] = head[i];
  ws[(size_t)48 * kNPIX + pix] = Sall;
}

// ---------------- Kernel B: R assembly + Cholesky + solves ----------------
__global__ __launch_bounds__(256, 1) void mvb_solve_kernel(
    const float* __restrict__ ws, float* __restrict__ out) {
  const int pix = blockIdx.x * 256 + threadIdx.x;

  float F[16], win[16], head[16];
#pragma unroll
  for (int i = 0; i < 16; ++i) F[i] = ws[(size_t)i * kNPIX + pix];
#pragma unroll
  for (int i = 0; i < 16; ++i) win[i] = ws[(size_t)(16 + i) * kNPIX + pix];
#pragma unroll
  for (int i = 0; i < 16; ++i) head[i] = ws[(size_t)(32 + i) * kNPIX + pix];
  const float Sall = ws[(size_t)48 * kNPIX + pix];

  // ---- assemble R (unscaled by 1/M; packed upper triangle) ----
  float Ru[136];
#pragma unroll
  for (int d = 0; d < 16; ++d) {
    float t0s = 0.0f;                      // tail beyond window of l=0
#pragma unroll
    for (int i = d + 1; i < 16; ++i) t0s = fmaf(win[i - d], win[i], t0s);
    Ru[tri(0, d)] = F[d] - t0s;
#pragma unroll
    for (int l = 1; l < 16 - d; ++l)
      Ru[tri(l, l + d)] = Ru[tri(l - 1, l - 1 + d)] -
                          head[l - 1] * head[l - 1 + d] +
                          win[l] * win[l + d];
  }

  // diagonal loading: += DL * trace/16
  float tr = 0.0f;
#pragma unroll
  for (int l = 0; l < 16; ++l) tr += Ru[tri(l, l)];
  const float dl = tr * (0.05f / 16.0f);
#pragma unroll
  for (int l = 0; l < 16; ++l) Ru[tri(l, l)] += dl;

  // x (unscaled window means): X[l] = sum_{j=l}^{l+112} xf[j]
  float X[16];
  {
    float s = Sall;
#pragma unroll
    for (int i = 1; i < 16; ++i) s -= win[i];
    X[0] = s;
#pragma unroll
    for (int l = 1; l < 16; ++l) X[l] = X[l - 1] - head[l - 1] + win[l];
  }

  // ---- Cholesky R = L L^T, L[i][j] stored at Ru[tri(j,i)] ----
  float inv[16];
#pragma unroll
  for (int j = 0; j < 16; ++j) {
    float d = Ru[tri(j, j)];
#pragma unroll
    for (int p = 0; p < j; ++p) d = fmaf(-Ru[tri(p, j)], Ru[tri(p, j)], d);
    float Ljj = sqrtf(d);
    inv[j] = 1.0f / Ljj;
    Ru[tri(j, j)] = Ljj;
#pragma unroll
    for (int i = j + 1; i < 16; ++i) {
      float s = Ru[tri(j, i)];
#pragma unroll
      for (int p = 0; p < j; ++p) s = fmaf(-Ru[tri(p, i)], Ru[tri(p, j)], s);
      Ru[tri(j, i)] = s * inv[j];
    }
  }

  // forward solve L y = 1
  float yv[16];
#pragma unroll
  for (int i = 0; i < 16; ++i) {
    float s = 1.0f;
#pragma unroll
    for (int j = 0; j < i; ++j) s = fmaf(-Ru[tri(j, i)], yv[j], s);
    yv[i] = s * inv[i];
  }
  // back solve L^T u = y
  float u[16];
#pragma unroll
  for (int i = 15; i >= 0; --i) {
    float s = yv[i];
#pragma unroll
    for (int j = i + 1; j < 16; ++j) s = fmaf(-Ru[tri(i, j)], u[j], s);
    u[i] = s * inv[i];
  }

  float su = 0.0f, dot = 0.0f;
#pragma unroll
  for (int i = 0; i < 16; ++i) {
    su += u[i];
    dot = fmaf(u[i], X[i], dot);
  }
  // y = dot/(M*su + 1e-10)  (matches reference up to scale algebra)
  out[pix] = dot / (113.0f * su + 1e-10f);
}

}  // namespace

extern "C" void kernel_launch(void* const* d_in, const int* in_sizes, int n_in,
                              void* d_out, int out_size, void* d_ws,
                              size_t ws_size, hipStream_t stream) {
  const float* rf   = (const float*)d_in[0];
  const float* t0   = (const float*)d_in[1];
  const float* d_tx = (const float*)d_in[2];
  const float* d_rx = (const float*)d_in[3];
  const float* fs   = (const float*)d_in[4];
  // d_in[5] = f0 (unused), d_in[7] = apod (unused by reference)
  const float* c0   = (const float*)d_in[6];
  float* out = (float*)d_out;
  float* ws  = (float*)d_ws;   // needs 49 * 65536 * 4 B = 12.85 MB

  hipLaunchKernelGGL(mvb_window_kernel, dim3(kB * kNZ), dim3(kTPB), 0, stream,
                     rf, t0, d_tx, d_rx, fs, c0, ws);
  hipLaunchKernelGGL(mvb_solve_kernel, dim3(kNPIX / 256), dim3(256), 0, stream,
                     ws, out);
}

// Round 3
// 105.920 us; speedup vs baseline: 1.5302x; 1.5302x over previous
//
#include <hip/hip_runtime.h>

// MVB (minimum-variance beamformer), fp32. Round 3.
//
// Round-2 diagnosis: pre[] (prefetch registers) was captured by reference in
// lambdas -> address taken -> SROA failure -> whole array demoted to scratch
// (4 KB/thread stored = the observed ~122 MB spill traffic). Fix: stage rf
// chunks with __builtin_amdgcn_global_load_lds (global->LDS DMA, width 16),
// which needs NO intermediate registers and no lambdas.
//
// Kernel A: per-pixel delay-align + rolling 16-lag window sums.
//   rf staged to LDS in double-buffered 8-row (32 KB) chunks via
//   global_load_lds; chunk q+1 issued async before computing chunk q
//   (one __syncthreads per chunk = the vmcnt drain point).
//   Writes F[16], win[16], head[16], Sall (49 floats/pixel) to d_ws,
//   feature-major for coalescing.
// Kernel B: R assembly (lag identity) + diag loading + Cholesky + solves.

namespace {

constexpr int kB  = 2;
constexpr int kC  = 128;
constexpr int kNS = 1024;
constexpr int kNZ = 256;
constexpr int kNX = 128;
constexpr int kZX = kNZ * kNX;      // 32768
constexpr int kNPIX = kB * kZX;     // 65536
constexpr int kChunk = 8;           // rf rows per stage (32 KB)
constexpr int kTPB = 128;

// packed upper-triangular index, l <= k, 16x16 -> 136 entries
__device__ __host__ constexpr int tri(int l, int k) {
  return l * 16 - (l * (l - 1)) / 2 + (k - l);
}

typedef __attribute__((address_space(1))) const void gconst_t;
typedef __attribute__((address_space(3))) void ldsv_t;

__device__ __forceinline__ void g2l16(const float* g, float* l) {
  // 16B per lane, LDS dest = wave-uniform base + lane*16
  __builtin_amdgcn_global_load_lds((gconst_t*)g, (ldsv_t*)l, 16, 0, 0);
}

// Stage one 32 KB chunk (8 rf rows) global->LDS, async. Per wave: 16 issues
// of 64 lanes x 16 B = 1 KB contiguous. woff = wave*256 floats, so the two
// waves cover each 2 KB stripe.
__device__ __forceinline__ void stage_chunk(const float* __restrict__ gsrc,
                                            float* lbase, int woff, int lane) {
#pragma unroll
  for (int i = 0; i < 16; ++i)
    g2l16(gsrc + i * 512 + woff + lane * 4, lbase + i * 512 + woff);
}

template <int PH, bool HEAD>
__device__ __forceinline__ void chunk_compute(
    const float (&rows)[kChunk][kNS], int cbase,
    const float* __restrict__ drx_px, float kk, float base,
    float (&F)[16], float (&win)[16], float (&head)[16], float& Sall) {
  float drx[kChunk];
#pragma unroll
  for (int r = 0; r < kChunk; ++r)
    drx[r] = drx_px[(size_t)(cbase + r) * kZX];   // coalesced across lanes

#pragma unroll
  for (int r = 0; r < kChunk; ++r) {
    const int t = PH + r;                          // == c & 15 (static)
    float pos = fmaf(kk, drx[r], base);
    pos = fminf(fmaxf(pos, 0.0f), 1023.0f);
    int i0 = (int)pos;                             // pos >= 0: trunc == floor
    float frac = pos - (float)i0;
    int i1 = min(i0 + 1, kNS - 1);
    float v0 = rows[r][i0];                        // ds_read, random bank
    float v1 = rows[r][i1];
    float v = fmaf(frac, v1 - v0, v0);
    Sall += v;
    F[0] = fmaf(v, v, F[0]);
    if constexpr (HEAD) {
#pragma unroll
      for (int d = 1; d <= t; ++d) F[d] = fmaf(v, win[t - d], F[d]);
      head[t] = v;
    } else {
#pragma unroll
      for (int d = 1; d < 16; ++d) F[d] = fmaf(v, win[(t - d) & 15], F[d]);
    }
    win[t] = v;
  }
}

// ---------------- Kernel A: window accumulation ----------------
__global__ __launch_bounds__(kTPB, 1) void mvb_window_kernel(
    const float* __restrict__ rf, const float* __restrict__ t0,
    const float* __restrict__ d_tx, const float* __restrict__ d_rx,
    const float* __restrict__ fs_p, const float* __restrict__ c0_p,
    float* __restrict__ ws) {
  __shared__ float tile[2][kChunk][kNS];   // 64 KB -> 2 blocks/CU

  const int tid = threadIdx.x;
  const int lane = tid & 63;
  const int wave = tid >> 6;
  const int woff = wave * 256;             // floats
  const int z = blockIdx.x & (kNZ - 1);
  const int b = blockIdx.x >> 8;           // kNZ == 256
  const int x = tid;
  const int pix = (int)((size_t)b * kZX + z * kNX + x);

  const float fs = fs_p[0];
  const float c0 = c0_p[0];
  const float kk = fs / c0;
  const float base =
      fs * (d_tx[(size_t)b * kZX + z * kNX + x] / c0 + t0[b]);

  const float* rfb = rf + (size_t)b * kC * kNS;
  const float* drx_px = d_rx + (size_t)z * kNX + x;   // + c*kZX per channel

  float F[16], win[16], head[16];
  float Sall = 0.0f;
#pragma unroll
  for (int i = 0; i < 16; ++i) F[i] = 0.0f;

  // ---- pipelined loop over 16 chunks of 8 channels, double-buffered ----
  stage_chunk(rfb, &tile[0][0][0], woff, lane);                 // chunk 0
  __syncthreads();

  stage_chunk(rfb + 1 * kChunk * kNS, &tile[1][0][0], woff, lane);  // chunk 1
  chunk_compute<0, true>(tile[0], 0, drx_px, kk, base, F, win, head, Sall);
  __syncthreads();

  stage_chunk(rfb + 2 * kChunk * kNS, &tile[0][0][0], woff, lane);  // chunk 2
  chunk_compute<8, true>(tile[1], 8, drx_px, kk, base, F, win, head, Sall);
  __syncthreads();

  for (int g = 0; g < 7; ++g) {
    const int q0 = 2 * g + 2;
    stage_chunk(rfb + (size_t)(q0 + 1) * kChunk * kNS, &tile[1][0][0], woff,
                lane);
    chunk_compute<0, false>(tile[0], q0 * kChunk, drx_px, kk, base, F, win,
                            head, Sall);
    __syncthreads();

    if (q0 + 2 < 16)
      stage_chunk(rfb + (size_t)(q0 + 2) * kChunk * kNS, &tile[0][0][0], woff,
                  lane);
    chunk_compute<8, false>(tile[1], (q0 + 1) * kChunk, drx_px, kk, base, F,
                            win, head, Sall);
    __syncthreads();
  }
  // now: head[i] = xf[i], win[i] = xf[112+i], F[d] = sum_j xf[j]*xf[j-d]

  // ---- write per-pixel summary, feature-major for coalescing ----
#pragma unroll
  for (int i = 0; i < 16; ++i) ws[(size_t)i * kNPIX + pix] = F[i];
#pragma unroll
  for (int i = 0; i < 16; ++i) ws[(size_t)(16 + i) * kNPIX + pix] = win[i];
#pragma unroll
  for (int i = 0; i < 16; ++i) ws[(size_t)(32 + i) * kNPIX + pix] = head[i];
  ws[(size_t)48 * kNPIX + pix] = Sall;
}

// ---------------- Kernel B: R assembly + Cholesky + solves ----------------
__global__ __launch_bounds__(256, 1) void mvb_solve_kernel(
    const float* __restrict__ ws, float* __restrict__ out) {
  const int pix = blockIdx.x * 256 + threadIdx.x;

  float F[16], win[16], head[16];
#pragma unroll
  for (int i = 0; i < 16; ++i) F[i] = ws[(size_t)i * kNPIX + pix];
#pragma unroll
  for (int i = 0; i < 16; ++i) win[i] = ws[(size_t)(16 + i) * kNPIX + pix];
#pragma unroll
  for (int i = 0; i < 16; ++i) head[i] = ws[(size_t)(32 + i) * kNPIX + pix];
  const float Sall = ws[(size_t)48 * kNPIX + pix];

  // ---- assemble R (unscaled by 1/M; packed upper triangle) ----
  float Ru[136];
#pragma unroll
  for (int d = 0; d < 16; ++d) {
    float t0s = 0.0f;                      // tail beyond window of l=0
#pragma unroll
    for (int i = d + 1; i < 16; ++i) t0s = fmaf(win[i - d], win[i], t0s);
    Ru[tri(0, d)] = F[d] - t0s;
#pragma unroll
    for (int l = 1; l < 16 - d; ++l)
      Ru[tri(l, l + d)] = Ru[tri(l - 1, l - 1 + d)] -
                          head[l - 1] * head[l - 1 + d] +
                          win[l] * win[l + d];
  }

  // diagonal loading: += DL * trace/16
  float tr = 0.0f;
#pragma unroll
  for (int l = 0; l < 16; ++l) tr += Ru[tri(l, l)];
  const float dl = tr * (0.05f / 16.0f);
#pragma unroll
  for (int l = 0; l < 16; ++l) Ru[tri(l, l)] += dl;

  // x (unscaled window sums): X[l] = sum_{j=l}^{l+112} xf[j]
  float X[16];
  {
    float s = Sall;
#pragma unroll
    for (int i = 1; i < 16; ++i) s -= win[i];
    X[0] = s;
#pragma unroll
    for (int l = 1; l < 16; ++l) X[l] = X[l - 1] - head[l - 1] + win[l];
  }

  // ---- Cholesky R = L L^T, L[i][j] stored at Ru[tri(j,i)] ----
  float inv[16];
#pragma unroll
  for (int j = 0; j < 16; ++j) {
    float d = Ru[tri(j, j)];
#pragma unroll
    for (int p = 0; p < j; ++p) d = fmaf(-Ru[tri(p, j)], Ru[tri(p, j)], d);
    float Ljj = sqrtf(d);
    inv[j] = 1.0f / Ljj;
    Ru[tri(j, j)] = Ljj;
#pragma unroll
    for (int i = j + 1; i < 16; ++i) {
      float s = Ru[tri(j, i)];
#pragma unroll
      for (int p = 0; p < j; ++p) s = fmaf(-Ru[tri(p, i)], Ru[tri(p, j)], s);
      Ru[tri(j, i)] = s * inv[j];
    }
  }

  // forward solve L y = 1
  float yv[16];
#pragma unroll
  for (int i = 0; i < 16; ++i) {
    float s = 1.0f;
#pragma unroll
    for (int j = 0; j < i; ++j) s = fmaf(-Ru[tri(j, i)], yv[j], s);
    yv[i] = s * inv[i];
  }
  // back solve L^T u = y
  float u[16];
#pragma unroll
  for (int i = 15; i >= 0; --i) {
    float s = yv[i];
#pragma unroll
    for (int j = i + 1; j < 16; ++j) s = fmaf(-Ru[tri(i, j)], u[j], s);
    u[i] = s * inv[i];
  }

  float su = 0.0f, dot = 0.0f;
#pragma unroll
  for (int i = 0; i < 16; ++i) {
    su += u[i];
    dot = fmaf(u[i], X[i], dot);
  }
  // y = dot/(M*su + 1e-10)  (matches reference up to scale algebra)
  out[pix] = dot / (113.0f * su + 1e-10f);
}

}  // namespace

extern "C" void kernel_launch(void* const* d_in, const int* in_sizes, int n_in,
                              void* d_out, int out_size, void* d_ws,
                              size_t ws_size, hipStream_t stream) {
  const float* rf   = (const float*)d_in[0];
  const float* t0   = (const float*)d_in[1];
  const float* d_tx = (const float*)d_in[2];
  const float* d_rx = (const float*)d_in[3];
  const float* fs   = (const float*)d_in[4];
  // d_in[5] = f0 (unused), d_in[7] = apod (unused by reference)
  const float* c0   = (const float*)d_in[6];
  float* out = (float*)d_out;
  float* ws  = (float*)d_ws;   // needs 49 * 65536 * 4 B = 12.85 MB

  hipLaunchKernelGGL(mvb_window_kernel, dim3(kB * kNZ), dim3(kTPB), 0, stream,
                     rf, t0, d_tx, d_rx, fs, c0, ws);
  hipLaunchKernelGGL(mvb_solve_kernel, dim3(kNPIX / 256), dim3(256), 0, stream,
                     ws, out);
}

// Round 4
// 100.152 us; speedup vs baseline: 1.6183x; 1.0576x over previous
//
#include <hip/hip_runtime.h>

// MVB (minimum-variance beamformer), fp32. Round 4.
//
// Round-3 result: spills gone; total now dominated by harness overhead
// (268 MB d_ws 0xAA poison fill ~45us/iter) + ~50us of A+B.
// Round-4 changes:
//  - Kernel A: 256-thread blocks = 2 z-rows (grid 256, 1 block/CU): halves
//    rf->LDS staging traffic per CU (268->134 MB aggregate through L2).
//  - drx software-prefetched one chunk ahead (register double-buffer).
//  - Gather: i0 = min(i0,1022), read p[0],p[1] adjacent -> ds_read2_b32
//    merge, no separate i1 clamp (pos==1023 -> frac=1.0 -> == v[1023]).
//  - Kernel B: 64-thread blocks, __launch_bounds__(64,1) -> full VGPR
//    budget for Ru[136], spill-proof.

namespace {

constexpr int kB  = 2;
constexpr int kC  = 128;
constexpr int kNS = 1024;
constexpr int kNZ = 256;
constexpr int kNX = 128;
constexpr int kZX = kNZ * kNX;      // 32768
constexpr int kNPIX = kB * kZX;     // 65536
constexpr int kChunk = 8;           // rf rows per stage (32 KB)
constexpr int kChunkF = kChunk * kNS;   // 8192 floats
constexpr int kTPA = 256;           // kernel A block: 2 z-rows

// packed upper-triangular index, l <= k, 16x16 -> 136 entries
__device__ __host__ constexpr int tri(int l, int k) {
  return l * 16 - (l * (l - 1)) / 2 + (k - l);
}

typedef __attribute__((address_space(1))) const void gconst_t;
typedef __attribute__((address_space(3))) void ldsv_t;

__device__ __forceinline__ void g2l16(const float* g, float* l) {
  // 16B per lane, LDS dest = wave-uniform base + lane*16
  __builtin_amdgcn_global_load_lds((gconst_t*)g, (ldsv_t*)l, 16, 0, 0);
}

// Stage one 32 KB chunk (8 rf rows) global->LDS, async.
// 4 waves x 8 issues x (64 lanes x 16 B) = 32 KB. woff = wave*2048 floats.
__device__ __forceinline__ void stage_chunk(const float* __restrict__ gsrc,
                                            float* ldst, int woff, int lane) {
#pragma unroll
  for (int i = 0; i < 8; ++i)
    g2l16(gsrc + woff + i * 256 + lane * 4, ldst + woff + i * 256);
}

__device__ __forceinline__ void load_drx(const float* __restrict__ drx_px,
                                         int cbase, float (&d)[kChunk]) {
#pragma unroll
  for (int r = 0; r < kChunk; ++r)
    d[r] = drx_px[(size_t)(cbase + r) * kZX];   // coalesced across lanes
}

template <int PH, bool HEAD>
__device__ __forceinline__ void chunk_compute(
    const float* rows, const float (&drx)[kChunk], float kk, float base,
    float (&F)[16], float (&win)[16], float (&head)[16], float& Sall) {
#pragma unroll
  for (int r = 0; r < kChunk; ++r) {
    const int t = PH + r;                          // == c & 15 (static)
    float pos = fmaf(kk, drx[r], base);
    pos = fminf(fmaxf(pos, 0.0f), 1023.0f);
    int i0 = (int)pos;                             // pos >= 0: trunc == floor
    i0 = min(i0, kNS - 2);                         // pos==1023 -> frac==1.0
    float frac = pos - (float)i0;
    const float* p = rows + r * kNS + i0;
    float v0 = p[0];                               // ds_read2_b32 pair
    float v1 = p[1];
    float v = fmaf(frac, v1 - v0, v0);
    Sall += v;
    F[0] = fmaf(v, v, F[0]);
    if constexpr (HEAD) {
#pragma unroll
      for (int d = 1; d <= t; ++d) F[d] = fmaf(v, win[t - d], F[d]);
      head[t] = v;
    } else {
#pragma unroll
      for (int d = 1; d < 16; ++d) F[d] = fmaf(v, win[(t - d) & 15], F[d]);
    }
    win[t] = v;
  }
}

// ---------------- Kernel A: window accumulation ----------------
__global__ __launch_bounds__(kTPA, 1) void mvb_window_kernel(
    const float* __restrict__ rf, const float* __restrict__ t0,
    const float* __restrict__ d_tx, const float* __restrict__ d_rx,
    const float* __restrict__ fs_p, const float* __restrict__ c0_p,
    float* __restrict__ ws) {
  __shared__ float tile[2 * kChunkF];      // 64 KB, double buffer

  const int tid = threadIdx.x;
  const int lane = tid & 63;
  const int wave = tid >> 6;
  const int woff = wave * 2048;            // floats (staging stripe)
  const int b = blockIdx.x >> 7;           // 256 blocks: b in {0,1}
  const int z = ((blockIdx.x & 127) << 1) + (tid >> 7);
  const int x = tid & 127;
  const int pix = (int)((size_t)b * kZX + z * kNX + x);

  const float fs = fs_p[0];
  const float c0 = c0_p[0];
  const float kk = fs / c0;
  const float base = fs * (d_tx[pix] / c0 + t0[b]);

  const float* rfb = rf + (size_t)b * kC * kNS;
  const float* drx_px = d_rx + (size_t)z * kNX + x;   // + c*kZX per channel

  float F[16], win[16], head[16];
  float Sall = 0.0f;
#pragma unroll
  for (int i = 0; i < 16; ++i) F[i] = 0.0f;

  float drx0[kChunk], drx1[kChunk];

  // ---- pipelined loop over 16 chunks of 8 channels, double-buffered ----
  stage_chunk(rfb, tile, woff, lane);                         // chunk 0
  load_drx(drx_px, 0, drx0);
  __syncthreads();

  stage_chunk(rfb + kChunkF, tile + kChunkF, woff, lane);     // chunk 1
  load_drx(drx_px, 8, drx1);
  chunk_compute<0, true>(tile, drx0, kk, base, F, win, head, Sall);
  __syncthreads();

  stage_chunk(rfb + 2 * kChunkF, tile, woff, lane);           // chunk 2
  load_drx(drx_px, 16, drx0);
  chunk_compute<8, true>(tile + kChunkF, drx1, kk, base, F, win, head, Sall);
  __syncthreads();

  for (int g = 0; g < 7; ++g) {
    const int q0 = 2 * g + 2;
    stage_chunk(rfb + (size_t)(q0 + 1) * kChunkF, tile + kChunkF, woff, lane);
    load_drx(drx_px, (q0 + 1) * kChunk, drx1);
    chunk_compute<0, false>(tile, drx0, kk, base, F, win, head, Sall);
    __syncthreads();

    if (q0 + 2 < 16) {
      stage_chunk(rfb + (size_t)(q0 + 2) * kChunkF, tile, woff, lane);
      load_drx(drx_px, (q0 + 2) * kChunk, drx0);
    }
    chunk_compute<8, false>(tile + kChunkF, drx1, kk, base, F, win, head,
                            Sall);
    __syncthreads();
  }
  // now: head[i] = xf[i], win[i] = xf[112+i], F[d] = sum_j xf[j]*xf[j-d]

  // ---- write per-pixel summary, feature-major for coalescing ----
#pragma unroll
  for (int i = 0; i < 16; ++i) ws[(size_t)i * kNPIX + pix] = F[i];
#pragma unroll
  for (int i = 0; i < 16; ++i) ws[(size_t)(16 + i) * kNPIX + pix] = win[i];
#pragma unroll
  for (int i = 0; i < 16; ++i) ws[(size_t)(32 + i) * kNPIX + pix] = head[i];
  ws[(size_t)48 * kNPIX + pix] = Sall;
}

// ---------------- Kernel B: R assembly + Cholesky + solves ----------------
__global__ __launch_bounds__(64, 1) void mvb_solve_kernel(
    const float* __restrict__ ws, float* __restrict__ out) {
  const int pix = blockIdx.x * 64 + threadIdx.x;

  float F[16], win[16], head[16];
#pragma unroll
  for (int i = 0; i < 16; ++i) F[i] = ws[(size_t)i * kNPIX + pix];
#pragma unroll
  for (int i = 0; i < 16; ++i) win[i] = ws[(size_t)(16 + i) * kNPIX + pix];
#pragma unroll
  for (int i = 0; i < 16; ++i) head[i] = ws[(size_t)(32 + i) * kNPIX + pix];
  const float Sall = ws[(size_t)48 * kNPIX + pix];

  // ---- assemble R (unscaled by 1/M; packed upper triangle) ----
  float Ru[136];
#pragma unroll
  for (int d = 0; d < 16; ++d) {
    float t0s = 0.0f;                      // tail beyond window of l=0
#pragma unroll
    for (int i = d + 1; i < 16; ++i) t0s = fmaf(win[i - d], win[i], t0s);
    Ru[tri(0, d)] = F[d] - t0s;
#pragma unroll
    for (int l = 1; l < 16 - d; ++l)
      Ru[tri(l, l + d)] = Ru[tri(l - 1, l - 1 + d)] -
                          head[l - 1] * head[l - 1 + d] +
                          win[l] * win[l + d];
  }

  // diagonal loading: += DL * trace/16
  float tr = 0.0f;
#pragma unroll
  for (int l = 0; l < 16; ++l) tr += Ru[tri(l, l)];
  const float dl = tr * (0.05f / 16.0f);
#pragma unroll
  for (int l = 0; l < 16; ++l) Ru[tri(l, l)] += dl;

  // x (unscaled window sums): X[l] = sum_{j=l}^{l+112} xf[j]
  float X[16];
  {
    float s = Sall;
#pragma unroll
    for (int i = 1; i < 16; ++i) s -= win[i];
    X[0] = s;
#pragma unroll
    for (int l = 1; l < 16; ++l) X[l] = X[l - 1] - head[l - 1] + win[l];
  }

  // ---- Cholesky R = L L^T, L[i][j] stored at Ru[tri(j,i)] ----
  float inv[16];
#pragma unroll
  for (int j = 0; j < 16; ++j) {
    float d = Ru[tri(j, j)];
#pragma unroll
    for (int p = 0; p < j; ++p) d = fmaf(-Ru[tri(p, j)], Ru[tri(p, j)], d);
    float Ljj = sqrtf(d);
    inv[j] = 1.0f / Ljj;
    Ru[tri(j, j)] = Ljj;
#pragma unroll
    for (int i = j + 1; i < 16; ++i) {
      float s = Ru[tri(j, i)];
#pragma unroll
      for (int p = 0; p < j; ++p) s = fmaf(-Ru[tri(p, i)], Ru[tri(p, j)], s);
      Ru[tri(j, i)] = s * inv[j];
    }
  }

  // forward solve L y = 1
  float yv[16];
#pragma unroll
  for (int i = 0; i < 16; ++i) {
    float s = 1.0f;
#pragma unroll
    for (int j = 0; j < i; ++j) s = fmaf(-Ru[tri(j, i)], yv[j], s);
    yv[i] = s * inv[i];
  }
  // back solve L^T u = y
  float u[16];
#pragma unroll
  for (int i = 15; i >= 0; --i) {
    float s = yv[i];
#pragma unroll
    for (int j = i + 1; j < 16; ++j) s = fmaf(-Ru[tri(i, j)], u[j], s);
    u[i] = s * inv[i];
  }

  float su = 0.0f, dot = 0.0f;
#pragma unroll
  for (int i = 0; i < 16; ++i) {
    su += u[i];
    dot = fmaf(u[i], X[i], dot);
  }
  // y = dot/(M*su + 1e-10)  (matches reference up to scale algebra)
  out[pix] = dot / (113.0f * su + 1e-10f);
}

}  // namespace

extern "C" void kernel_launch(void* const* d_in, const int* in_sizes, int n_in,
                              void* d_out, int out_size, void* d_ws,
                              size_t ws_size, hipStream_t stream) {
  const float* rf   = (const float*)d_in[0];
  const float* t0   = (const float*)d_in[1];
  const float* d_tx = (const float*)d_in[2];
  const float* d_rx = (const float*)d_in[3];
  const float* fs   = (const float*)d_in[4];
  // d_in[5] = f0 (unused), d_in[7] = apod (unused by reference)
  const float* c0   = (const float*)d_in[6];
  float* out = (float*)d_out;
  float* ws  = (float*)d_ws;   // needs 49 * 65536 * 4 B = 12.85 MB

  hipLaunchKernelGGL(mvb_window_kernel, dim3(kB * kNZ / 2), dim3(kTPA), 0,
                     stream, rf, t0, d_tx, d_rx, fs, c0, ws);
  hipLaunchKernelGGL(mvb_solve_kernel, dim3(kNPIX / 64), dim3(64), 0, stream,
                     ws, out);
}

// Round 5
// 95.440 us; speedup vs baseline: 1.6982x; 1.0494x over previous
//
#include <hip/hip_runtime.h>

// MVB (minimum-variance beamformer), fp32. Round 5: fused single kernel.
//
// Round-4 budget: dur 100.2 = 43 (harness d_ws poison fill, unavoidable)
// + ~5 restores + ~5-10 graph gaps + ~40 A+B. Fusion removes the 26 MB ws
// round-trip and one dispatch; 128-thread blocks x 512 give 2 independent
// blocks/CU so one block computes while the other sits at its barrier.
//
// Phase A (per-pixel): rf staged to LDS in double-buffered 8-row (32 KB)
//   chunks via global_load_lds (no intermediate VGPRs -> no SROA spills);
//   bilinear gather + rolling 16-lag window sums (F/win/head/Sall).
// Phase B (same thread): R via lag identity + diag loading + Cholesky
//   (rsqrt form) + two triangular solves + weighted sum -> out.
// Peak ~220 VGPRs at LB(128,1): within the 512 budget, no spill.

namespace {

constexpr int kB  = 2;
constexpr int kC  = 128;
constexpr int kNS = 1024;
constexpr int kNZ = 256;
constexpr int kNX = 128;
constexpr int kZX = kNZ * kNX;          // 32768
constexpr int kChunk = 8;               // rf rows per stage (32 KB)
constexpr int kChunkF = kChunk * kNS;   // 8192 floats
constexpr int kTPB = 128;

// packed upper-triangular index, l <= k, 16x16 -> 136 entries
__device__ __host__ constexpr int tri(int l, int k) {
  return l * 16 - (l * (l - 1)) / 2 + (k - l);
}

typedef __attribute__((address_space(1))) const void gconst_t;
typedef __attribute__((address_space(3))) void ldsv_t;

__device__ __forceinline__ void g2l16(const float* g, float* l) {
  // 16B per lane, LDS dest = wave-uniform base + lane*16
  __builtin_amdgcn_global_load_lds((gconst_t*)g, (ldsv_t*)l, 16, 0, 0);
}

// Stage one 32 KB chunk (8 rf rows) global->LDS, async.
// 2 waves x 16 issues x (64 lanes x 16 B) = 32 KB. woff = wave*4096 floats.
__device__ __forceinline__ void stage_chunk(const float* __restrict__ gsrc,
                                            float* ldst, int woff, int lane) {
#pragma unroll
  for (int i = 0; i < 16; ++i)
    g2l16(gsrc + woff + i * 256 + lane * 4, ldst + woff + i * 256);
}

__device__ __forceinline__ void load_drx(const float* __restrict__ drx_px,
                                         int cbase, float (&d)[kChunk]) {
#pragma unroll
  for (int r = 0; r < kChunk; ++r)
    d[r] = drx_px[(size_t)(cbase + r) * kZX];   // coalesced across lanes
}

template <int PH, bool HEAD>
__device__ __forceinline__ void chunk_compute(
    const float* rows, const float (&drx)[kChunk], float kk, float base,
    float (&F)[16], float (&win)[16], float (&head)[16], float& Sall) {
#pragma unroll
  for (int r = 0; r < kChunk; ++r) {
    const int t = PH + r;                          // == c & 15 (static)
    float pos = fmaf(kk, drx[r], base);
    pos = fminf(fmaxf(pos, 0.0f), 1023.0f);
    int i0 = (int)pos;                             // pos >= 0: trunc == floor
    i0 = min(i0, kNS - 2);                         // pos==1023 -> frac==1.0
    float frac = pos - (float)i0;
    const float* p = rows + r * kNS + i0;
    float v0 = p[0];                               // ds_read2_b32 pair
    float v1 = p[1];
    float v = fmaf(frac, v1 - v0, v0);
    Sall += v;
    F[0] = fmaf(v, v, F[0]);
    if constexpr (HEAD) {
#pragma unroll
      for (int d = 1; d <= t; ++d) F[d] = fmaf(v, win[t - d], F[d]);
      head[t] = v;
    } else {
#pragma unroll
      for (int d = 1; d < 16; ++d) F[d] = fmaf(v, win[(t - d) & 15], F[d]);
    }
    win[t] = v;
  }
}

// ---------------- Fused kernel: window + covariance + solve ----------------
__global__ __launch_bounds__(kTPB, 1) void mvb_fused_kernel(
    const float* __restrict__ rf, const float* __restrict__ t0,
    const float* __restrict__ d_tx, const float* __restrict__ d_rx,
    const float* __restrict__ fs_p, const float* __restrict__ c0_p,
    float* __restrict__ out) {
  __shared__ float tile[2 * kChunkF];      // 64 KB double buffer -> 2 blk/CU

  const int tid = threadIdx.x;
  const int lane = tid & 63;
  const int wave = tid >> 6;
  const int woff = wave * 4096;            // staging stripe (floats)
  const int z = blockIdx.x & (kNZ - 1);
  const int b = blockIdx.x >> 8;           // kNZ == 256
  const int x = tid;
  const int pix = (int)((size_t)b * kZX + z * kNX + x);

  const float fs = fs_p[0];
  const float c0 = c0_p[0];
  const float kk = fs / c0;
  const float base = fs * (d_tx[pix] / c0 + t0[b]);

  const float* rfb = rf + (size_t)b * kC * kNS;
  const float* drx_px = d_rx + (size_t)z * kNX + x;   // + c*kZX per channel

  float F[16], win[16], head[16];
  float Sall = 0.0f;
#pragma unroll
  for (int i = 0; i < 16; ++i) F[i] = 0.0f;

  float drx0[kChunk], drx1[kChunk];

  // ---- phase A: pipelined loop over 16 chunks of 8 channels ----
  stage_chunk(rfb, tile, woff, lane);                         // chunk 0
  load_drx(drx_px, 0, drx0);
  __syncthreads();

  stage_chunk(rfb + kChunkF, tile + kChunkF, woff, lane);     // chunk 1
  load_drx(drx_px, 8, drx1);
  chunk_compute<0, true>(tile, drx0, kk, base, F, win, head, Sall);
  __syncthreads();

  stage_chunk(rfb + 2 * kChunkF, tile, woff, lane);           // chunk 2
  load_drx(drx_px, 16, drx0);
  chunk_compute<8, true>(tile + kChunkF, drx1, kk, base, F, win, head, Sall);
  __syncthreads();

  for (int g = 0; g < 7; ++g) {
    const int q0 = 2 * g + 2;
    stage_chunk(rfb + (size_t)(q0 + 1) * kChunkF, tile + kChunkF, woff, lane);
    load_drx(drx_px, (q0 + 1) * kChunk, drx1);
    chunk_compute<0, false>(tile, drx0, kk, base, F, win, head, Sall);
    __syncthreads();

    if (q0 + 2 < 16) {
      stage_chunk(rfb + (size_t)(q0 + 2) * kChunkF, tile, woff, lane);
      load_drx(drx_px, (q0 + 2) * kChunk, drx0);
    }
    chunk_compute<8, false>(tile + kChunkF, drx1, kk, base, F, win, head,
                            Sall);
    __syncthreads();
  }
  // now: head[i] = xf[i], win[i] = xf[112+i], F[d] = sum_j xf[j]*xf[j-d]

  // ---- phase B: assemble R (unscaled; packed upper triangle) ----
  float Ru[136];
#pragma unroll
  for (int d = 0; d < 16; ++d) {
    float t0s = 0.0f;                      // tail beyond window of l=0
#pragma unroll
    for (int i = d + 1; i < 16; ++i) t0s = fmaf(win[i - d], win[i], t0s);
    Ru[tri(0, d)] = F[d] - t0s;
#pragma unroll
    for (int l = 1; l < 16 - d; ++l)
      Ru[tri(l, l + d)] = Ru[tri(l - 1, l - 1 + d)] -
                          head[l - 1] * head[l - 1 + d] +
                          win[l] * win[l + d];
  }

  // diagonal loading: += DL * trace/16
  float tr = 0.0f;
#pragma unroll
  for (int l = 0; l < 16; ++l) tr += Ru[tri(l, l)];
  const float dl = tr * (0.05f / 16.0f);
#pragma unroll
  for (int l = 0; l < 16; ++l) Ru[tri(l, l)] += dl;

  // x (unscaled window sums): X[l] = sum_{j=l}^{l+112} xf[j]
  float X[16];
  {
    float s = Sall;
#pragma unroll
    for (int i = 1; i < 16; ++i) s -= win[i];
    X[0] = s;
#pragma unroll
    for (int l = 1; l < 16; ++l) X[l] = X[l - 1] - head[l - 1] + win[l];
  }

  // ---- Cholesky R = L L^T (rsqrt form), L[i][j] at Ru[tri(j,i)] ----
  // L[j][j] is only ever used through inv[j] = 1/L[j][j] = rsqrt(d).
  float inv[16];
#pragma unroll
  for (int j = 0; j < 16; ++j) {
    float d = Ru[tri(j, j)];
#pragma unroll
    for (int p = 0; p < j; ++p) d = fmaf(-Ru[tri(p, j)], Ru[tri(p, j)], d);
    inv[j] = rsqrtf(d);
#pragma unroll
    for (int i = j + 1; i < 16; ++i) {
      float s = Ru[tri(j, i)];
#pragma unroll
      for (int p = 0; p < j; ++p) s = fmaf(-Ru[tri(p, i)], Ru[tri(p, j)], s);
      Ru[tri(j, i)] = s * inv[j];
    }
  }

  // forward solve L y = 1
  float yv[16];
#pragma unroll
  for (int i = 0; i < 16; ++i) {
    float s = 1.0f;
#pragma unroll
    for (int j = 0; j < i; ++j) s = fmaf(-Ru[tri(j, i)], yv[j], s);
    yv[i] = s * inv[i];
  }
  // back solve L^T u = y
  float u[16];
#pragma unroll
  for (int i = 15; i >= 0; --i) {
    float s = yv[i];
#pragma unroll
    for (int j = i + 1; j < 16; ++j) s = fmaf(-Ru[tri(i, j)], u[j], s);
    u[i] = s * inv[i];
  }

  float su = 0.0f, dot = 0.0f;
#pragma unroll
  for (int i = 0; i < 16; ++i) {
    su += u[i];
    dot = fmaf(u[i], X[i], dot);
  }
  // y = dot/(M*su + 1e-10)  (matches reference up to scale algebra)
  out[pix] = dot / (113.0f * su + 1e-10f);
}

}  // namespace

extern "C" void kernel_launch(void* const* d_in, const int* in_sizes, int n_in,
                              void* d_out, int out_size, void* d_ws,
                              size_t ws_size, hipStream_t stream) {
  const float* rf   = (const float*)d_in[0];
  const float* t0   = (const float*)d_in[1];
  const float* d_tx = (const float*)d_in[2];
  const float* d_rx = (const float*)d_in[3];
  const float* fs   = (const float*)d_in[4];
  // d_in[5] = f0 (unused), d_in[7] = apod (unused by reference)
  const float* c0   = (const float*)d_in[6];
  float* out = (float*)d_out;

  hipLaunchKernelGGL(mvb_fused_kernel, dim3(kB * kNZ), dim3(kTPB), 0, stream,
                     rf, t0, d_tx, d_rx, fs, c0, out);
}